// Round 11
// baseline (103.926 us; speedup 1.0000x reference)
//
#include <hip/hip_runtime.h>
#include <hip/hip_bf16.h>

#define B_DIM 16
#define KQ    2048
#define W_DIM 2048
#define D_DIM 128
#define QBLK  128
#define KVB   32
#define NT    (W_DIM / KVB)   // 64
#define TILEB 24576           // bytes per (b,t) ws tile == per LDS buffer
#define TILEU 12288           // u16 per tile

typedef float f4 __attribute__((ext_vector_type(4)));
typedef float f32x16 __attribute__((ext_vector_type(16)));
typedef __bf16 bf16x8 __attribute__((ext_vector_type(8)));
typedef unsigned short u16x4 __attribute__((ext_vector_type(4)));
typedef unsigned short u16x8 __attribute__((ext_vector_type(8)));

static __device__ __forceinline__ unsigned short f2bf(float x) {
  __bf16 h = (__bf16)x;
  return __builtin_bit_cast(unsigned short, h);
}

// ws tile layout per (b,t), byte-identical to one LDS buffer:
//   K1 [0,8192):    32 k-rows x 256B; 16B chunk c stored at c' = c ^ (k&7)
//   K2 [8192,16384): same
//   V^T [16384,24576): 128 d-rows x 64B; logical chunk h=2ks+hi stored at
//       h' = h ^ ((d>>1)&3); slot j of chunk (ks,hi) holds V[k=16ks+4hi+(j&3)+8(j>>2)][d]
__global__ __launch_bounds__(256, 2)
void prepass(const float* __restrict__ K1g, const float* __restrict__ K2g,
             const float* __restrict__ Vg, unsigned short* __restrict__ ws)
{
  __shared__ unsigned short lv[KVB][132];
  const int tid = threadIdx.x;
  const int bt  = blockIdx.x;               // b*NT + t
  const size_t gsrc = (size_t)bt * KVB * D_DIM;
  unsigned short* wt = ws + (size_t)bt * TILEU;

#pragma unroll
  for (int uu = 0; uu < 2; ++uu) {
    const int unit = uu * 256 + tid;
    const int k = unit >> 4, c = unit & 15;
    const float* s1 = K1g + gsrc + k * D_DIM + c * 8;
    const float* s2 = K2g + gsrc + k * D_DIM + c * 8;
    f4 a0 = *(const f4*)s1, a1 = *(const f4*)(s1 + 4);
    f4 b0 = *(const f4*)s2, b1 = *(const f4*)(s2 + 4);
    u16x8 o1 = { f2bf(a0[0]), f2bf(a0[1]), f2bf(a0[2]), f2bf(a0[3]),
                 f2bf(a1[0]), f2bf(a1[1]), f2bf(a1[2]), f2bf(a1[3]) };
    u16x8 o2 = { f2bf(b0[0]), f2bf(b0[1]), f2bf(b0[2]), f2bf(b0[3]),
                 f2bf(b1[0]), f2bf(b1[1]), f2bf(b1[2]), f2bf(b1[3]) };
    const int cp = c ^ (k & 7);
    *(u16x8*)(wt + k * 128 + cp * 8)        = o1;
    *(u16x8*)(wt + 4096 + k * 128 + cp * 8) = o2;
  }

#pragma unroll
  for (int uu = 0; uu < 4; ++uu) {
    const int fi = uu * 256 + tid;
    const int k = fi >> 5, d4 = (fi & 31) * 4;
    f4 v = *(const f4*)(Vg + gsrc + k * D_DIM + d4);
    *(u16x4*)&lv[k][d4] = (u16x4){ f2bf(v[0]), f2bf(v[1]), f2bf(v[2]), f2bf(v[3]) };
  }
  __syncthreads();

#pragma unroll
  for (int uu = 0; uu < 2; ++uu) {
    const int unit = uu * 256 + tid;
    const int d = unit >> 2, hp = unit & 3;
    const int h = hp ^ ((d >> 1) & 3);
    const int ks = h >> 1, hi = h & 1;
    u16x8 ov;
#pragma unroll
    for (int j = 0; j < 8; ++j) {
      const int k = 16 * ks + 4 * hi + (j & 3) + 8 * (j >> 2);
      ov[j] = lv[k][d];
    }
    *(u16x8*)(wt + 8192 + d * 32 + hp * 8) = ov;
  }
}

// ---------------- main: 64 q/wave, 1 block/CU, 512-VGPR budget ----------------
// Wave = (stream s, q-half qh) x 64 q (2 chunks of 32). Per iter: 8 K-reads +
// 8 V-reads feed 32 MFMAs (QK qc0 + QK qc1 + PV(t-1) both qc). T15 pipeline,
// triple LDS buffer + trash buffer for tail dup-stages, counted vmcnt(6).
__global__ __launch_bounds__(256, 1)
void diffattn(const float* __restrict__ Q1g, const float* __restrict__ Q2g,
              const unsigned short* __restrict__ ws,
              const float* __restrict__ lamp, float* __restrict__ Og)
{
  __shared__ char smem[4 * TILEB];   // 96KB: 3 rotating + 1 trash; epi reuses [0,64K)

  const int tid  = threadIdx.x;
  const int wv   = tid >> 6;     // 0..3
  const int lane = tid & 63;
  const int hi   = lane >> 5;
  const int ln   = lane & 31;
  const int s    = wv & 1;       // stream
  const int qh   = wv >> 1;      // q half (64 rows)

  // XCD-aware bijective swizzle: 256 = 8 XCDs x 32
  const int wg  = blockIdx.x;
  const int swz = (wg & 7) * 32 + (wg >> 3);
  const int qt  = swz & 15;
  const int b   = swz >> 4;
  const int q0  = qt * QBLK;

  const float qscale = 0.08838834764831845f * 1.4426950408889634f; // 1/sqrt(128)*log2(e)

  // ---- Q fragments: 2 q-chunks x 8 d-steps (B-operand, lane = q-col ln)
  const float* Qs = s ? Q2g : Q1g;
  bf16x8 qf[2][8];
#pragma unroll
  for (int qc = 0; qc < 2; ++qc) {
    const float* qp = Qs + ((size_t)b * KQ + q0 + qh * 64 + qc * 32 + ln) * D_DIM + hi * 8;
#pragma unroll
    for (int st = 0; st < 8; ++st) {
      f4 lo = *(const f4*)(qp + st * 16);
      f4 h4 = *(const f4*)(qp + st * 16 + 4);
      bf16x8 tq;
#pragma unroll
      for (int j = 0; j < 4; ++j) {
        tq[j]     = (__bf16)(lo[j] * qscale);
        tq[4 + j] = (__bf16)(h4[j] * qscale);
      }
      qf[qc][st] = tq;
    }
  }

  f32x16 o[2][4];
#pragma unroll
  for (int qc = 0; qc < 2; ++qc)
#pragma unroll
    for (int db = 0; db < 4; ++db)
#pragma unroll
      for (int i = 0; i < 16; ++i) o[qc][db][i] = 0.f;

  float lsp[2][2] = {{0.f, 0.f}, {0.f, 0.f}};   // split row-sum partials per q-chunk

  // ---- addresses ----
  const unsigned short* wsb = ws + (size_t)b * NT * TILEU;
  int kaddr[8];
#pragma unroll
  for (int st = 0; st < 8; ++st)
    kaddr[st] = s * 8192 + ln * 256 + (((2 * st + hi) ^ (ln & 7)) << 4);
  const int vb0 = 16384 + ln * 64;
  int vswz[2];
#pragma unroll
  for (int ks = 0; ks < 2; ++ks) vswz[ks] = (((2 * ks + hi) ^ ((ln >> 1) & 3)) << 4);

  auto STAGE = [&](int t, char* dB) {
    const unsigned short* sp0 = wsb + (size_t)t * TILEU + lane * 8;
#pragma unroll
    for (int i = 0; i < 6; ++i) {
      const int ch = wv * 6 + i;
      __builtin_amdgcn_global_load_lds(
          (const __attribute__((address_space(1))) void*)(sp0 + ch * 512),
          (__attribute__((address_space(3))) void*)(dB + ch * 1024), 16, 0, 0);
    }
  };

  char* pA = smem;
  char* pB = smem + TILEB;
  char* pC = smem + 2 * TILEB;
  char* const trash = smem + 3 * TILEB;

  STAGE(0, pA);
  STAGE(1, pB);
  __builtin_amdgcn_sched_barrier(0);
  asm volatile("s_waitcnt vmcnt(6)" ::: "memory");   // tile 0 resident
  __builtin_amdgcn_s_barrier();
  __builtin_amdgcn_sched_barrier(0);

  bf16x8 paP[2][2];   // P fragments of tile t-1, per q-chunk
  bf16x8 vvP[8];      // V fragments of tile t-1 (shared across q-chunks)

#pragma unroll 1
  for (int t = 0; t < NT; ++t) {
    // tail dup-stages go to the trash buffer (keeps vmcnt counting valid,
    // never read, can't race the epilogue's LDS reuse)
    const bool live = (t + 2 < NT);
    STAGE(live ? t + 2 : NT - 1, live ? pC : trash);

    // ---- one contiguous MFMA burst: QK(t,qc0) + QK(t,qc1) + PV(t-1) ----
    f32x16 s0, s1, s2, s3;
#pragma unroll
    for (int i = 0; i < 16; ++i) { s0[i] = 0.f; s1[i] = 0.f; s2[i] = 0.f; s3[i] = 0.f; }
    __builtin_amdgcn_s_setprio(1);
#pragma unroll
    for (int st = 0; st < 4; ++st) {
      const bf16x8 a0 = *(const bf16x8*)(pA + kaddr[st]);
      const bf16x8 a1 = *(const bf16x8*)(pA + kaddr[st + 4]);
      s0 = __builtin_amdgcn_mfma_f32_32x32x16_bf16(a0, qf[0][st], s0, 0, 0, 0);
      s1 = __builtin_amdgcn_mfma_f32_32x32x16_bf16(a1, qf[0][st + 4], s1, 0, 0, 0);
      s2 = __builtin_amdgcn_mfma_f32_32x32x16_bf16(a0, qf[1][st], s2, 0, 0, 0);
      s3 = __builtin_amdgcn_mfma_f32_32x32x16_bf16(a1, qf[1][st + 4], s3, 0, 0, 0);
    }
    if (t) {
#pragma unroll
      for (int db = 0; db < 4; ++db)
#pragma unroll
        for (int ks = 0; ks < 2; ++ks) {
          o[0][db] = __builtin_amdgcn_mfma_f32_32x32x16_bf16(paP[0][ks], vvP[db * 2 + ks], o[0][db], 0, 0, 0);
          o[1][db] = __builtin_amdgcn_mfma_f32_32x32x16_bf16(paP[1][ks], vvP[db * 2 + ks], o[1][db], 0, 0, 0);
        }
    }
    __builtin_amdgcn_s_setprio(0);

    // ---- unnormalized exp2 (raw v_exp_f32); P packed into A-fragments ----
#pragma unroll
    for (int ks = 0; ks < 2; ++ks) {
      bf16x8 pv0, pv1;
#pragma unroll
      for (int j = 0; j < 8; ++j) {
        const float p0 = __builtin_amdgcn_exp2f(s0[8 * ks + j] + s1[8 * ks + j]);
        const float p1 = __builtin_amdgcn_exp2f(s2[8 * ks + j] + s3[8 * ks + j]);
        lsp[0][j & 1] += p0;
        lsp[1][j & 1] += p1;
        pv0[j] = (__bf16)p0;   // slot j <-> k = 16ks + 4hi + (j&3) + 8(j>>2)
        pv1[j] = (__bf16)p1;
      }
      paP[0][ks] = pv0;        // overwrite AFTER PV(t-1) consumed previous
      paP[1][ks] = pv1;
    }

    // ---- V fragments of tile t -> registers (consumed next iter) ----
#pragma unroll
    for (int db = 0; db < 4; ++db)
#pragma unroll
      for (int ks = 0; ks < 2; ++ks)
        vvP[db * 2 + ks] = *(const bf16x8*)(pA + vb0 + db * 2048 + vswz[ks]);

    __builtin_amdgcn_sched_barrier(0);
    asm volatile("s_waitcnt vmcnt(6) lgkmcnt(0)" ::: "memory");
    __builtin_amdgcn_s_barrier();
    __builtin_amdgcn_sched_barrier(0);

    char* tmp = pA; pA = pB; pB = pC; pC = tmp;
  }

  // ---- final PV for tile NT-1 ----
#pragma unroll
  for (int db = 0; db < 4; ++db)
#pragma unroll
    for (int ks = 0; ks < 2; ++ks) {
      o[0][db] = __builtin_amdgcn_mfma_f32_32x32x16_bf16(paP[0][ks], vvP[db * 2 + ks], o[0][db], 0, 0, 0);
      o[1][db] = __builtin_amdgcn_mfma_f32_32x32x16_bf16(paP[1][ks], vvP[db * 2 + ks], o[1][db], 0, 0, 0);
    }

  // ---- epilogue: reduce l, combine streams via LDS [0,64K) ----
  const float lam = 1.f / (1.f + __expf(-lamp[0]));
  float lt[2], wq[2][16];
#pragma unroll
  for (int qc = 0; qc < 2; ++qc) {
    float x = lsp[qc][0] + lsp[qc][1];
    lt[qc] = x + __shfl_xor(x, 32);
  }
  const float fac = s ? lam : 1.f;
#pragma unroll
  for (int qc = 0; qc < 2; ++qc)
#pragma unroll
    for (int r = 0; r < 16; ++r)
      wq[qc][r] = fac / __shfl(lt[qc], (r & 3) + 8 * (r >> 2) + 4 * hi);

  if (s == 1) {
#pragma unroll
    for (int qc = 0; qc < 2; ++qc)
#pragma unroll
      for (int db = 0; db < 4; ++db)
#pragma unroll
        for (int r = 0; r < 16; ++r) {
          const int q = qh * 64 + qc * 32 + (r & 3) + 8 * (r >> 2) + 4 * hi;
          *(float*)(smem + q * 512 + (db * 32 + ln) * 4) = o[qc][db][r] * wq[qc][r];
        }
  }
  __syncthreads();
  if (s == 0) {
    float* op = Og + ((size_t)b * KQ + q0) * D_DIM;
#pragma unroll
    for (int qc = 0; qc < 2; ++qc)
#pragma unroll
      for (int db = 0; db < 4; ++db)
#pragma unroll
        for (int r = 0; r < 16; ++r) {
          const int q = qh * 64 + qc * 32 + (r & 3) + 8 * (r >> 2) + 4 * hi;
          const float o2v = *(const float*)(smem + q * 512 + (db * 32 + ln) * 4);
          op[q * D_DIM + db * 32 + ln] = o[qc][db][r] * wq[qc][r] - o2v;
        }
  }
}

extern "C" void kernel_launch(void* const* d_in, const int* in_sizes, int n_in,
                              void* d_out, int out_size, void* d_ws, size_t ws_size,
                              hipStream_t stream) {
  const float* Q1 = (const float*)d_in[0];
  const float* Q2 = (const float*)d_in[1];
  const float* K1 = (const float*)d_in[2];
  const float* K2 = (const float*)d_in[3];
  const float* V  = (const float*)d_in[4];
  const float* lm = (const float*)d_in[5];
  float* O = (float*)d_out;

  unsigned short* wsp = (unsigned short*)d_ws;   // 24 MB

  prepass<<<dim3(B_DIM * NT), dim3(256), 0, stream>>>(K1, K2, V, wsp);
  diffattn<<<dim3(B_DIM * (KQ / QBLK)), dim3(256), 0, stream>>>(Q1, Q2, wsp, lm, O);
}

// Round 12
// 100.665 us; speedup vs baseline: 1.0324x; 1.0324x over previous
//
#include <hip/hip_runtime.h>
#include <hip/hip_bf16.h>

#define B_DIM 16
#define KQ    2048
#define W_DIM 2048
#define D_DIM 128
#define QBLK  64
#define KVB   32
#define NT    (W_DIM / KVB)   // 64
#define KSEG  16384           // K1+K2 LDS bytes per buffer (= staged part of a tile)
#define TILEU 12288           // u16 per ws tile (K 16KB + V 8KB)

typedef float f4 __attribute__((ext_vector_type(4)));
typedef float f32x16 __attribute__((ext_vector_type(16)));
typedef __bf16 bf16x8 __attribute__((ext_vector_type(8)));
typedef unsigned short u16x4 __attribute__((ext_vector_type(4)));
typedef unsigned short u16x8 __attribute__((ext_vector_type(8)));

static __device__ __forceinline__ unsigned short f2bf(float x) {
  __bf16 h = (__bf16)x;
  return __builtin_bit_cast(unsigned short, h);
}

// ws tile layout per (b,t):
//   K1 [u16 0,4096):    32 k-rows x 256B; 16B chunk c stored at c' = c ^ (k&7)
//   K2 [u16 4096,8192):  same
//   V  [u16 8192,12288): 8 contiguous 1KB fragments, chunk ch = db*2+ks;
//       lane l (=hi*32+ln) holds 16B: slot j = V[k=16ks+4hi+(j&3)+8(j>>2)][d=db*32+ln]
//       (exact PV B-operand layout -> global->reg, fully coalesced)
__global__ __launch_bounds__(256, 2)
void prepass(const float* __restrict__ K1g, const float* __restrict__ K2g,
             const float* __restrict__ Vg, unsigned short* __restrict__ ws)
{
  __shared__ unsigned short lv[KVB][132];
  const int tid = threadIdx.x;
  const int bt  = blockIdx.x;               // b*NT + t
  const size_t gsrc = (size_t)bt * KVB * D_DIM;
  unsigned short* wt = ws + (size_t)bt * TILEU;

  // ---- K1/K2: convert + chunk-swizzle ----
#pragma unroll
  for (int uu = 0; uu < 2; ++uu) {
    const int unit = uu * 256 + tid;
    const int k = unit >> 4, c = unit & 15;
    const float* s1 = K1g + gsrc + k * D_DIM + c * 8;
    const float* s2 = K2g + gsrc + k * D_DIM + c * 8;
    f4 a0 = *(const f4*)s1, a1 = *(const f4*)(s1 + 4);
    f4 b0 = *(const f4*)s2, b1 = *(const f4*)(s2 + 4);
    u16x8 o1 = { f2bf(a0[0]), f2bf(a0[1]), f2bf(a0[2]), f2bf(a0[3]),
                 f2bf(a1[0]), f2bf(a1[1]), f2bf(a1[2]), f2bf(a1[3]) };
    u16x8 o2 = { f2bf(b0[0]), f2bf(b0[1]), f2bf(b0[2]), f2bf(b0[3]),
                 f2bf(b1[0]), f2bf(b1[1]), f2bf(b1[2]), f2bf(b1[3]) };
    const int cp = c ^ (k & 7);
    *(u16x8*)(wt + k * 128 + cp * 8)        = o1;
    *(u16x8*)(wt + 4096 + k * 128 + cp * 8) = o2;
  }

  // ---- V: stage bf16 tile ----
#pragma unroll
  for (int uu = 0; uu < 4; ++uu) {
    const int fi = uu * 256 + tid;
    const int k = fi >> 5, d4 = (fi & 31) * 4;
    f4 v = *(const f4*)(Vg + gsrc + k * D_DIM + d4);
    *(u16x4*)&lv[k][d4] = (u16x4){ f2bf(v[0]), f2bf(v[1]), f2bf(v[2]), f2bf(v[3]) };
  }
  __syncthreads();

  // ---- V: emit per-fragment contiguous chunks ----
#pragma unroll
  for (int uu = 0; uu < 2; ++uu) {
    const int unit = uu * 256 + tid;   // 0..511 = ch(0..7) x l(0..63)
    const int ch = unit >> 6;
    const int l  = unit & 63;
    const int ks = ch & 1;
    const int db = ch >> 1;
    const int h2 = l >> 5, l2 = l & 31;
    const int d  = db * 32 + l2;
    u16x8 ov;
#pragma unroll
    for (int j = 0; j < 8; ++j) {
      const int k = 16 * ks + 4 * h2 + (j & 3) + 8 * (j >> 2);
      ov[j] = lv[k][d];
    }
    *(u16x8*)(wt + 8192 + ch * 512 + l * 8) = ov;
  }
}

// ---------------- main: K via LDS (shared), V via global->reg ----------------
// Per iter: STAGE K(t+2) [4 gload_lds] -> MFMA burst QK(t)+PV(t-1) [8 ds_read
// + 16 MFMA] -> exp -> V(t) global->reg [8 dwordx4, consumed next iter] ->
// lgkmcnt(0) + raw s_barrier. Compiler's counted vmcnt for the V regs also
// drains the older K(t+1) stage loads (queue order), so no manual vmcnt.
__global__ __launch_bounds__(256, 2)
void diffattn(const float* __restrict__ Q1g, const float* __restrict__ Q2g,
              const unsigned short* __restrict__ ws,
              const float* __restrict__ lamp, float* __restrict__ Og)
{
  __shared__ char smem[4 * KSEG];   // 3 rotating K buffers + trash; epi reuses [0,32K)

  const int tid  = threadIdx.x;
  const int wv   = tid >> 6;     // 0..3
  const int lane = tid & 63;
  const int hi   = lane >> 5;
  const int ln   = lane & 31;
  const int s    = wv & 1;       // stream
  const int qh   = wv >> 1;      // q chunk (32 rows)

  // XCD-aware bijective swizzle: 512 = 8 XCDs x 64
  const int wg  = blockIdx.x;
  const int swz = (wg & 7) * 64 + (wg >> 3);
  const int qt  = swz & 31;
  const int b   = swz >> 5;
  const int q0  = qt * QBLK;

  const float qscale = 0.08838834764831845f * 1.4426950408889634f; // 1/sqrt(128)*log2(e)

  // ---- Q fragments (B-operand): lane = q-col ln, d-slots hi*8+j+16*step
  const float* Qs = s ? Q2g : Q1g;
  bf16x8 qf[8];
  {
    const float* qp = Qs + ((size_t)b * KQ + q0 + qh * 32 + ln) * D_DIM + hi * 8;
#pragma unroll
    for (int st = 0; st < 8; ++st) {
      f4 lo = *(const f4*)(qp + st * 16);
      f4 h4 = *(const f4*)(qp + st * 16 + 4);
      bf16x8 tq;
#pragma unroll
      for (int j = 0; j < 4; ++j) {
        tq[j]     = (__bf16)(lo[j] * qscale);
        tq[4 + j] = (__bf16)(h4[j] * qscale);
      }
      qf[st] = tq;
    }
  }

  f32x16 o[4];
#pragma unroll
  for (int db = 0; db < 4; ++db)
#pragma unroll
    for (int i = 0; i < 16; ++i) o[db][i] = 0.f;

  float lsp[2] = {0.f, 0.f};

  // ---- addresses ----
  const unsigned short* wsb = ws + (size_t)b * NT * TILEU;
  int kaddr[8];
#pragma unroll
  for (int st = 0; st < 8; ++st)
    kaddr[st] = s * 8192 + ln * 256 + (((2 * st + hi) ^ (ln & 7)) << 4);

  auto STAGE = [&](int t, char* dB) {
    const unsigned short* sp0 = wsb + (size_t)t * TILEU + lane * 8;
#pragma unroll
    for (int i = 0; i < 4; ++i) {
      const int ch = wv * 4 + i;
      __builtin_amdgcn_global_load_lds(
          (const __attribute__((address_space(1))) void*)(sp0 + ch * 512),
          (__attribute__((address_space(3))) void*)(dB + ch * 1024), 16, 0, 0);
    }
  };

  char* pA = smem;
  char* pB = smem + KSEG;
  char* pC = smem + 2 * KSEG;
  char* const trash = smem + 3 * KSEG;

  STAGE(0, pA);
  STAGE(1, pB);
  __builtin_amdgcn_sched_barrier(0);
  asm volatile("s_waitcnt vmcnt(4)" ::: "memory");   // K0 resident
  __builtin_amdgcn_s_barrier();
  __builtin_amdgcn_sched_barrier(0);

  bf16x8 paP[2];   // P fragments of tile t-1
  bf16x8 vvC[8];   // V fragments of tile t-1 (global->reg, idx = db*2+ks)

#pragma unroll 1
  for (int t = 0; t < NT; ++t) {
    const bool live = (t + 2 < NT);
    STAGE(live ? t + 2 : NT - 1, live ? pC : trash);

    // ---- one contiguous MFMA burst: QK(t) + PV(t-1) ----
    f32x16 s0, s1;
#pragma unroll
    for (int i = 0; i < 16; ++i) { s0[i] = 0.f; s1[i] = 0.f; }
    __builtin_amdgcn_s_setprio(1);
#pragma unroll
    for (int st = 0; st < 4; ++st) {
      const bf16x8 a0 = *(const bf16x8*)(pA + kaddr[st]);
      const bf16x8 a1 = *(const bf16x8*)(pA + kaddr[st + 4]);
      s0 = __builtin_amdgcn_mfma_f32_32x32x16_bf16(a0, qf[st], s0, 0, 0, 0);
      s1 = __builtin_amdgcn_mfma_f32_32x32x16_bf16(a1, qf[st + 4], s1, 0, 0, 0);
    }
    if (t) {
#pragma unroll
      for (int db = 0; db < 4; ++db)
#pragma unroll
        for (int ks = 0; ks < 2; ++ks)
          o[db] = __builtin_amdgcn_mfma_f32_32x32x16_bf16(paP[ks], vvC[db * 2 + ks], o[db], 0, 0, 0);
    }
    __builtin_amdgcn_s_setprio(0);

    // ---- unnormalized exp2 (raw v_exp_f32); P packed into A-fragments ----
#pragma unroll
    for (int ks = 0; ks < 2; ++ks) {
      bf16x8 pv;
#pragma unroll
      for (int j = 0; j < 8; ++j) {
        const float p = __builtin_amdgcn_exp2f(s0[8 * ks + j] + s1[8 * ks + j]);
        lsp[j & 1] += p;
        pv[j] = (__bf16)p;    // slot j <-> k = 16ks + 4hi + (j&3) + 8(j>>2)
      }
      paP[ks] = pv;           // overwrite AFTER PV(t-1) consumed previous
    }

    // ---- V(t) fragments: global->reg, consumed next iter ----
    {
      const unsigned short* vt = wsb + (size_t)t * TILEU + 8192 + lane * 8;
#pragma unroll
      for (int ch = 0; ch < 8; ++ch)
        vvC[ch] = *(const bf16x8*)(vt + ch * 512);
    }

    // ---- K ds_reads done -> barrier (buffer t%3 overwritten at t+1) ----
    __builtin_amdgcn_sched_barrier(0);
    asm volatile("s_waitcnt lgkmcnt(0)" ::: "memory");
    __builtin_amdgcn_s_barrier();
    __builtin_amdgcn_sched_barrier(0);

    char* tmp = pA; pA = pB; pB = pC; pC = tmp;
  }

  // ---- final PV for tile NT-1 (compiler waits the V loads) ----
#pragma unroll
  for (int db = 0; db < 4; ++db)
#pragma unroll
    for (int ks = 0; ks < 2; ++ks)
      o[db] = __builtin_amdgcn_mfma_f32_32x32x16_bf16(paP[ks], vvC[db * 2 + ks], o[db], 0, 0, 0);

  asm volatile("s_waitcnt vmcnt(0)" ::: "memory");   // drain trash stages

  // ---- epilogue: reduce l, combine streams via LDS [0,32K) ----
  const float lam = 1.f / (1.f + __expf(-lamp[0]));
  float ls = lsp[0] + lsp[1];
  const float lt  = ls + __shfl_xor(ls, 32);
  const float fac = s ? lam : 1.f;
  float wq[16];
#pragma unroll
  for (int r = 0; r < 16; ++r)
    wq[r] = fac / __shfl(lt, (r & 3) + 8 * (r >> 2) + 4 * hi);

  if (s == 1) {
#pragma unroll
    for (int db = 0; db < 4; ++db)
#pragma unroll
      for (int r = 0; r < 16; ++r) {
        const int q = qh * 32 + (r & 3) + 8 * (r >> 2) + 4 * hi;
        *(float*)(smem + q * 512 + (db * 32 + ln) * 4) = o[db][r] * wq[r];
      }
  }
  __syncthreads();
  if (s == 0) {
    float* op = Og + ((size_t)b * KQ + q0) * D_DIM;
#pragma unroll
    for (int db = 0; db < 4; ++db)
#pragma unroll
      for (int r = 0; r < 16; ++r) {
        const int q = qh * 32 + (r & 3) + 8 * (r >> 2) + 4 * hi;
        const float o2v = *(const float*)(smem + q * 512 + (db * 32 + ln) * 4);
        op[q * D_DIM + db * 32 + ln] = o[db][r] * wq[r] - o2v;
      }
  }
}

extern "C" void kernel_launch(void* const* d_in, const int* in_sizes, int n_in,
                              void* d_out, int out_size, void* d_ws, size_t ws_size,
                              hipStream_t stream) {
  const float* Q1 = (const float*)d_in[0];
  const float* Q2 = (const float*)d_in[1];
  const float* K1 = (const float*)d_in[2];
  const float* K2 = (const float*)d_in[3];
  const float* V  = (const float*)d_in[4];
  const float* lm = (const float*)d_in[5];
  float* O = (float*)d_out;

  unsigned short* wsp = (unsigned short*)d_ws;   // 24 MB

  prepass<<<dim3(B_DIM * NT), dim3(256), 0, stream>>>(K1, K2, V, wsp);
  diffattn<<<dim3(B_DIM * (KQ / QBLK)), dim3(256), 0, stream>>>(Q1, Q2, wsp, lm, O);
}